// Round 1
// baseline (1000.981 us; speedup 1.0000x reference)
//
#include <hip/hip_runtime.h>
#include <stdint.h>

#define M_ROWS 8192   // B*L
#define K_DIM  1024   // I
#define C_DIM  8192   // vocab
#define E_DIM  1024   // vq dim
#define NTILE  64     // C_DIM / 128
#define MARGIN 0.03f

typedef __bf16 bf16x8 __attribute__((ext_vector_type(8)));
typedef float  f32x4  __attribute__((ext_vector_type(4)));

union V16 { uint4 u; bf16x8 b; unsigned short s[8]; };

__device__ __forceinline__ unsigned short f2bf(float f) {
  union { float f; uint32_t u; } x; x.f = f;
  uint32_t r = (x.u + 0x7FFFu + ((x.u >> 16) & 1u)) >> 16;  // RNE
  return (unsigned short)r;
}

// ---------------- K1: fp32 -> bf16 convert ----------------
__global__ __launch_bounds__(256) void k_cvt_bf16(const float* __restrict__ in,
                                                  unsigned short* __restrict__ out,
                                                  int n4) {
  int i = blockIdx.x * 256 + threadIdx.x;
  if (i >= n4) return;
  float4 v = reinterpret_cast<const float4*>(in)[i];
  ushort4 o;
  o.x = f2bf(v.x); o.y = f2bf(v.y); o.z = f2bf(v.z); o.w = f2bf(v.w);
  reinterpret_cast<ushort4*>(out)[i] = o;
}

// ---------------- K2: transpose W_cb (E x C) -> (C x E) ----------------
__global__ __launch_bounds__(256) void k_transpose(const float* __restrict__ src,
                                                   float* __restrict__ dst) {
  __shared__ float t[32][33];
  const int c0 = blockIdx.x * 32, e0 = blockIdx.y * 32;
  const int x = threadIdx.x & 31, y0 = threadIdx.x >> 5;  // 32 x 8
#pragma unroll
  for (int i = 0; i < 4; ++i) {
    int y = y0 + i * 8;
    t[y][x] = src[(size_t)(e0 + y) * C_DIM + c0 + x];
  }
  __syncthreads();
#pragma unroll
  for (int i = 0; i < 4; ++i) {
    int y = y0 + i * 8;
    dst[(size_t)(c0 + y) * E_DIM + e0 + x] = t[x][y];
  }
}

__device__ __forceinline__ void top2_merge(float& v1, int& i1, float& v2, int& i2,
                                           float ov1, int oi1, float ov2, int oi2) {
  bool owin = (ov1 > v1) || (ov1 == v1 && oi1 < i1);
  if (owin) {
    bool keep = (v1 > ov2) || (v1 == ov2 && i1 < oi2);
    float nv2 = keep ? v1 : ov2; int ni2 = keep ? i1 : oi2;
    v1 = ov1; i1 = oi1; v2 = nv2; i2 = ni2;
  } else {
    bool rep = (ov1 > v2) || (ov1 == v2 && oi1 < i2);
    if (rep) { v2 = ov1; i2 = oi1; }
  }
}

// ---------------- K3: bf16 MFMA GEMM + gumbel + per-(row,128col) top2 ----------------
// 128x128 tile per block, 4 waves (2x2), wave tile 64x64, 16x16x32 bf16 MFMA, BK=64.
__global__ __launch_bounds__(256, 2) void k_gemm_top2(
    const unsigned short* __restrict__ Abf, const unsigned short* __restrict__ Wbf,
    const float* __restrict__ bvec, const float* __restrict__ gum,
    float4* __restrict__ top2g) {
  constexpr int LDT = 72;  // bf16 elems; 144B row stride = 9*16B -> bank-conflict-free
  __shared__ __align__(16) unsigned short As[128 * LDT];
  __shared__ __align__(16) unsigned short Bs[128 * LDT];
  __shared__ __align__(16) float4 mrg[128][2];

  const int bid = blockIdx.x;
  const int by = bid >> 6, bx = bid & 63;
  const int tid = threadIdx.x;
  const int lane = tid & 63, wave = tid >> 6;
  const int wy = wave >> 1, wx = wave & 1;
  const int q = lane >> 4, cl = lane & 15;

  f32x4 acc[4][4];
#pragma unroll
  for (int m_ = 0; m_ < 4; ++m_)
#pragma unroll
    for (int n_ = 0; n_ < 4; ++n_) acc[m_][n_] = (f32x4){0.f, 0.f, 0.f, 0.f};

  const int r_st = tid >> 3;  // staging: row, 8 threads x 16B per 128B row-chunk
  const int x_st = tid & 7;
  const size_t a_base = (size_t)(by * 128 + r_st) * K_DIM + x_st * 8;
  const size_t b_base = (size_t)(bx * 128 + r_st) * K_DIM + x_st * 8;

  for (int kt = 0; kt < 16; ++kt) {
    uint4 ra[4], rb[4];
    const int koff = kt * 64;
#pragma unroll
    for (int i = 0; i < 4; ++i) {
      ra[i] = *reinterpret_cast<const uint4*>(Abf + a_base + (size_t)i * 32 * K_DIM + koff);
      rb[i] = *reinterpret_cast<const uint4*>(Wbf + b_base + (size_t)i * 32 * K_DIM + koff);
    }
    __syncthreads();  // previous compute done before overwrite
#pragma unroll
    for (int i = 0; i < 4; ++i) {
      int r = r_st + i * 32;
      *reinterpret_cast<uint4*>(&As[r * LDT + x_st * 8]) = ra[i];
      *reinterpret_cast<uint4*>(&Bs[r * LDT + x_st * 8]) = rb[i];
    }
    __syncthreads();
#pragma unroll
    for (int ks = 0; ks < 2; ++ks) {
      V16 af[4], bfr[4];
#pragma unroll
      for (int m_ = 0; m_ < 4; ++m_)
        af[m_].u = *reinterpret_cast<const uint4*>(
            &As[(wy * 64 + m_ * 16 + cl) * LDT + ks * 32 + q * 8]);
#pragma unroll
      for (int n_ = 0; n_ < 4; ++n_)
        bfr[n_].u = *reinterpret_cast<const uint4*>(
            &Bs[(wx * 64 + n_ * 16 + cl) * LDT + ks * 32 + q * 8]);
#pragma unroll
      for (int m_ = 0; m_ < 4; ++m_)
#pragma unroll
        for (int n_ = 0; n_ < 4; ++n_)
          acc[m_][n_] = __builtin_amdgcn_mfma_f32_16x16x32_bf16(
              af[m_].b, bfr[n_].b, acc[m_][n_], 0, 0, 0);
    }
  }

  __syncthreads();
  const int row_base = by * 128;
  const int col_base = bx * 128 + wx * 64;
#pragma unroll
  for (int m_ = 0; m_ < 4; ++m_) {
#pragma unroll
    for (int reg = 0; reg < 4; ++reg) {
      const int lrow = wy * 64 + m_ * 16 + q * 4 + reg;  // C/D: row=(lane>>4)*4+reg
      const int grow = row_base + lrow;
      float v1 = -INFINITY, v2 = -INFINITY;
      int i1 = 0x7fffffff, i2 = 0x7fffffff;
#pragma unroll
      for (int n_ = 0; n_ < 4; ++n_) {
        const int gcol = col_base + n_ * 16 + cl;  // C/D: col=lane&15
        float z = acc[m_][n_][reg] + bvec[gcol] + gum[(size_t)grow * C_DIM + gcol];
        if (z > v1) { v2 = v1; i2 = i1; v1 = z; i1 = gcol; }
        else if (z > v2 || (z == v2 && gcol < i2)) { v2 = z; i2 = gcol; }
      }
#pragma unroll
      for (int d = 1; d < 16; d <<= 1) {  // butterfly within 16-lane group
        float ov1 = __shfl_xor(v1, d), ov2 = __shfl_xor(v2, d);
        int oi1 = __shfl_xor(i1, d), oi2 = __shfl_xor(i2, d);
        top2_merge(v1, i1, v2, i2, ov1, oi1, ov2, oi2);
      }
      if (cl == 0)
        mrg[lrow][wx] = make_float4(v1, __int_as_float(i1), v2, __int_as_float(i2));
    }
  }
  __syncthreads();
  if (tid < 128) {
    float4 a = mrg[tid][0], b = mrg[tid][1];
    float v1 = a.x, v2 = a.z;
    int i1 = __float_as_int(a.y), i2 = __float_as_int(a.w);
    top2_merge(v1, i1, v2, i2, b.x, __float_as_int(b.y), b.z, __float_as_int(b.w));
    top2g[(size_t)(row_base + tid) * NTILE + bx] =
        make_float4(v1, __int_as_float(i1), v2, __int_as_float(i2));
  }
}

// ---------------- K4: per-row candidate collect + fp64 exact rescore -> argmax ----------------
__global__ __launch_bounds__(256) void k_rescore(
    const float* __restrict__ A, const float* __restrict__ Wl,
    const float* __restrict__ bvec, const float* __restrict__ gum,
    const float4* __restrict__ top2g, int* __restrict__ ind) {
  const int row = blockIdx.x, tid = threadIdx.x;
  __shared__ int cidx[128];
  __shared__ int ccount;
  __shared__ float thr_s;
  __shared__ double red[256];
  if (tid == 0) ccount = 0;
  __syncthreads();
  float v1 = -INFINITY, v2 = -INFINITY;
  int i1 = 0, i2 = 0;
  if (tid < 64) {
    float4 e = top2g[(size_t)row * NTILE + tid];
    v1 = e.x; i1 = __float_as_int(e.y); v2 = e.z; i2 = __float_as_int(e.w);
    float g = v1;
#pragma unroll
    for (int d = 32; d; d >>= 1) g = fmaxf(g, __shfl_xor(g, d));
    if (tid == 0) thr_s = g - MARGIN;
  }
  __syncthreads();
  if (tid < 64) {
    float thr = thr_s;
    if (v1 >= thr) cidx[atomicAdd(&ccount, 1)] = i1;
    if (v2 >= thr) cidx[atomicAdd(&ccount, 1)] = i2;
  }
  __syncthreads();
  const int n = ccount;
  double bestv = -1e300; int besti = 0x7fffffff;
  const float* a = A + (size_t)row * K_DIM;
  for (int j = 0; j < n; ++j) {
    const int c = cidx[j];
    const float* w = Wl + (size_t)c * K_DIM;
    double s = 0.0;
    for (int k = tid; k < K_DIM; k += 256) s += (double)a[k] * (double)w[k];
    red[tid] = s; __syncthreads();
    for (int off = 128; off; off >>= 1) {
      if (tid < off) red[tid] += red[tid + off];
      __syncthreads();
    }
    if (tid == 0) {
      double z = red[0] + (double)bvec[c] + (double)gum[(size_t)row * C_DIM + c];
      if (z > bestv || (z == bestv && c < besti)) { bestv = z; besti = c; }
    }
    __syncthreads();
  }
  if (tid == 0) ind[row] = besti;
}

// ---------------- K5: gather codebook column ----------------
__global__ __launch_bounds__(256) void k_gather_T(const float* __restrict__ WcbT,
                                                  const int* __restrict__ ind,
                                                  float* __restrict__ out) {
  const int row = blockIdx.x;
  const int c = ind[row];
  const float4* src = reinterpret_cast<const float4*>(WcbT + (size_t)c * E_DIM);
  float4* dst = reinterpret_cast<float4*>(out + (size_t)row * E_DIM);
  dst[threadIdx.x] = src[threadIdx.x];  // 256 * 16B = 4KB row
}

__global__ __launch_bounds__(256) void k_gather_direct(const float* __restrict__ Wcb,
                                                       const int* __restrict__ ind,
                                                       float* __restrict__ out) {
  const int row = blockIdx.x;
  const int c = ind[row];
  for (int e = threadIdx.x; e < E_DIM; e += 256)
    out[(size_t)row * E_DIM + e] = Wcb[(size_t)e * C_DIM + c];
}

extern "C" void kernel_launch(void* const* d_in, const int* in_sizes, int n_in,
                              void* d_out, int out_size, void* d_ws, size_t ws_size,
                              hipStream_t stream) {
  const float* A   = (const float*)d_in[0];  // inputs (M x K)
  const float* Wl  = (const float*)d_in[1];  // W_logits (C x K)
  const float* bv  = (const float*)d_in[2];  // b_logits (C)
  const float* Wcb = (const float*)d_in[3];  // W_cb (E x C)
  const float* gum = (const float*)d_in[4];  // gumbel (M x C)
  float* out = (float*)d_out;

  char* ws = (char*)d_ws;
  size_t off = 0;
  unsigned short* Abf = (unsigned short*)(ws + off); off += (size_t)M_ROWS * K_DIM * 2;
  unsigned short* Wbf = (unsigned short*)(ws + off); off += (size_t)C_DIM * K_DIM * 2;
  float4* top2 = (float4*)(ws + off);                off += (size_t)M_ROWS * NTILE * 16;
  int* ind = (int*)(ws + off);                       off += (size_t)M_ROWS * 4;
  float* WcbT = (float*)(ws + off);
  const size_t need_full = off + (size_t)C_DIM * E_DIM * 4;
  const bool full = ws_size >= need_full;

  k_cvt_bf16<<<(M_ROWS * K_DIM / 4) / 256, 256, 0, stream>>>(A, Abf, M_ROWS * K_DIM / 4);
  k_cvt_bf16<<<(C_DIM * K_DIM / 4) / 256, 256, 0, stream>>>(Wl, Wbf, C_DIM * K_DIM / 4);
  if (full) {
    dim3 g(C_DIM / 32, E_DIM / 32);
    k_transpose<<<g, 256, 0, stream>>>(Wcb, WcbT);
  }
  k_gemm_top2<<<4096, 256, 0, stream>>>(Abf, Wbf, bv, gum, top2);
  k_rescore<<<M_ROWS, 256, 0, stream>>>(A, Wl, bv, gum, top2, ind);
  if (full) k_gather_T<<<M_ROWS, 256, 0, stream>>>(WcbT, ind, out);
  else      k_gather_direct<<<M_ROWS, 256, 0, stream>>>(Wcb, ind, out);
}

// Round 2
// 342.905 us; speedup vs baseline: 2.9191x; 2.9191x over previous
//
#include <hip/hip_runtime.h>
#include <stdint.h>

#define M_ROWS 8192   // B*L
#define K_DIM  1024   // I
#define C_DIM  8192   // vocab
#define E_DIM  1024   // vq dim
#define NTILE  64     // C_DIM / 128
#define MARGIN 0.03f

typedef __bf16 bf16x8 __attribute__((ext_vector_type(8)));
typedef float  f32x4  __attribute__((ext_vector_type(4)));

union V16 { uint4 u; bf16x8 b; unsigned short s[8]; };

__device__ __forceinline__ unsigned short f2bf(float f) {
  union { float f; uint32_t u; } x; x.f = f;
  uint32_t r = (x.u + 0x7FFFu + ((x.u >> 16) & 1u)) >> 16;  // RNE
  return (unsigned short)r;
}

// ---------------- K1: fp32 -> bf16 convert ----------------
__global__ __launch_bounds__(256) void k_cvt_bf16(const float* __restrict__ in,
                                                  unsigned short* __restrict__ out,
                                                  int n4) {
  int i = blockIdx.x * 256 + threadIdx.x;
  if (i >= n4) return;
  float4 v = reinterpret_cast<const float4*>(in)[i];
  ushort4 o;
  o.x = f2bf(v.x); o.y = f2bf(v.y); o.z = f2bf(v.z); o.w = f2bf(v.w);
  reinterpret_cast<ushort4*>(out)[i] = o;
}

// ---------------- K2: transpose W_cb (E x C) -> (C x E) ----------------
__global__ __launch_bounds__(256) void k_transpose(const float* __restrict__ src,
                                                   float* __restrict__ dst) {
  __shared__ float t[32][33];
  const int c0 = blockIdx.x * 32, e0 = blockIdx.y * 32;
  const int x = threadIdx.x & 31, y0 = threadIdx.x >> 5;  // 32 x 8
#pragma unroll
  for (int i = 0; i < 4; ++i) {
    int y = y0 + i * 8;
    t[y][x] = src[(size_t)(e0 + y) * C_DIM + c0 + x];
  }
  __syncthreads();
#pragma unroll
  for (int i = 0; i < 4; ++i) {
    int y = y0 + i * 8;
    dst[(size_t)(c0 + y) * E_DIM + e0 + x] = t[x][y];
  }
}

__device__ __forceinline__ void top2_merge(float& v1, int& i1, float& v2, int& i2,
                                           float ov1, int oi1, float ov2, int oi2) {
  bool owin = (ov1 > v1) || (ov1 == v1 && oi1 < i1);
  if (owin) {
    bool keep = (v1 > ov2) || (v1 == ov2 && i1 < oi2);
    float nv2 = keep ? v1 : ov2; int ni2 = keep ? i1 : oi2;
    v1 = ov1; i1 = oi1; v2 = nv2; i2 = ni2;
  } else {
    bool rep = (ov1 > v2) || (ov1 == v2 && oi1 < i2);
    if (rep) { v2 = ov1; i2 = oi1; }
  }
}

// ---------------- K3: bf16 MFMA GEMM + gumbel + per-(row,128col) top2 ----------------
// 128x128 tile per block, 4 waves (2x2), wave tile 64x64, 16x16x32 bf16 MFMA, BK=64.
// Staging via global_load_lds (16B), linear LDS [128][64] bf16; XOR swizzle applied to
// the per-lane GLOBAL source column and to the ds_read address (both-sides, rule #21).
__global__ __launch_bounds__(256, 2) void k_gemm_top2(
    const unsigned short* __restrict__ Abf, const unsigned short* __restrict__ Wbf,
    const float* __restrict__ bvec, const float* __restrict__ gum,
    float4* __restrict__ top2g) {
  __shared__ __align__(16) unsigned short As[128 * 64];  // 16 KB, linear row-major
  __shared__ __align__(16) unsigned short Bs[128 * 64];  // 16 KB
  __shared__ __align__(16) float4 mrg[128][2];           // 4 KB

  const int bid = blockIdx.x;
  const int by = bid >> 6, bx = bid & 63;
  const int tid = threadIdx.x;
  const int lane = tid & 63, wave = tid >> 6;
  const int wy = wave >> 1, wx = wave & 1;
  const int q = lane >> 4, cl = lane & 15;

  f32x4 acc[4][4];
#pragma unroll
  for (int m_ = 0; m_ < 4; ++m_)
#pragma unroll
    for (int n_ = 0; n_ < 4; ++n_) acc[m_][n_] = (f32x4){0.f, 0.f, 0.f, 0.f};

  // staging geometry: slot = pass*256 + tid; row = slot>>3 (0..127), x = slot&7
  const int r_st = tid >> 3;   // row within 32-row pass group
  const int x_st = tid & 7;    // 16B chunk index within 64-col row
  const char* Ab = (const char*)As;
  const char* Bb = (const char*)Bs;

  for (int kt = 0; kt < 16; ++kt) {
    __syncthreads();  // all ds_reads of previous tile complete before overwrite
    const int koff = kt * 64;
#pragma unroll
    for (int i = 0; i < 4; ++i) {
      const int row = i * 32 + r_st;
      const int xs = x_st ^ (row & 7);  // pre-swizzled global source column
      const unsigned short* ga = Abf + (size_t)(by * 128 + row) * K_DIM + koff + xs * 8;
      const unsigned short* gb = Wbf + (size_t)(bx * 128 + row) * K_DIM + koff + xs * 8;
      // wave-uniform LDS base (HW adds lane*16)
      unsigned short* la = (unsigned short*)As + i * 2048 + wave * 512;
      unsigned short* lb = (unsigned short*)Bs + i * 2048 + wave * 512;
      __builtin_amdgcn_global_load_lds(
          (const __attribute__((address_space(1))) unsigned int*)ga,
          (__attribute__((address_space(3))) unsigned int*)la, 16, 0, 0);
      __builtin_amdgcn_global_load_lds(
          (const __attribute__((address_space(1))) unsigned int*)gb,
          (__attribute__((address_space(3))) unsigned int*)lb, 16, 0, 0);
    }
    __syncthreads();  // vmcnt(0) drain: tile ready

#pragma unroll
    for (int ks = 0; ks < 2; ++ks) {
      V16 af[4], bfr[4];
#pragma unroll
      for (int m_ = 0; m_ < 4; ++m_) {
        const int arow = wy * 64 + m_ * 16 + cl;
        af[m_].u = *reinterpret_cast<const uint4*>(
            Ab + arow * 128 + ((((ks << 2) | q) ^ (arow & 7)) << 4));
      }
#pragma unroll
      for (int n_ = 0; n_ < 4; ++n_) {
        const int brow = wx * 64 + n_ * 16 + cl;
        bfr[n_].u = *reinterpret_cast<const uint4*>(
            Bb + brow * 128 + ((((ks << 2) | q) ^ (brow & 7)) << 4));
      }
#pragma unroll
      for (int m_ = 0; m_ < 4; ++m_)
#pragma unroll
        for (int n_ = 0; n_ < 4; ++n_)
          acc[m_][n_] = __builtin_amdgcn_mfma_f32_16x16x32_bf16(
              af[m_].b, bfr[n_].b, acc[m_][n_], 0, 0, 0);
    }
  }

  __syncthreads();
  const int row_base = by * 128;
  const int col_base = bx * 128 + wx * 64;
#pragma unroll
  for (int m_ = 0; m_ < 4; ++m_) {
#pragma unroll
    for (int reg = 0; reg < 4; ++reg) {
      const int lrow = wy * 64 + m_ * 16 + q * 4 + reg;  // C/D: row=(lane>>4)*4+reg
      const int grow = row_base + lrow;
      float v1 = -INFINITY, v2 = -INFINITY;
      int i1 = 0x7fffffff, i2 = 0x7fffffff;
#pragma unroll
      for (int n_ = 0; n_ < 4; ++n_) {
        const int gcol = col_base + n_ * 16 + cl;  // C/D: col=lane&15
        float z = acc[m_][n_][reg] + bvec[gcol] + gum[(size_t)grow * C_DIM + gcol];
        if (z > v1) { v2 = v1; i2 = i1; v1 = z; i1 = gcol; }
        else if (z > v2 || (z == v2 && gcol < i2)) { v2 = z; i2 = gcol; }
      }
#pragma unroll
      for (int d = 1; d < 16; d <<= 1) {  // butterfly within 16-lane group
        float ov1 = __shfl_xor(v1, d), ov2 = __shfl_xor(v2, d);
        int oi1 = __shfl_xor(i1, d), oi2 = __shfl_xor(i2, d);
        top2_merge(v1, i1, v2, i2, ov1, oi1, ov2, oi2);
      }
      if (cl == 0)
        mrg[lrow][wx] = make_float4(v1, __int_as_float(i1), v2, __int_as_float(i2));
    }
  }
  __syncthreads();
  if (tid < 128) {
    float4 a = mrg[tid][0], b = mrg[tid][1];
    float v1 = a.x, v2 = a.z;
    int i1 = __float_as_int(a.y), i2 = __float_as_int(a.w);
    top2_merge(v1, i1, v2, i2, b.x, __float_as_int(b.y), b.z, __float_as_int(b.w));
    top2g[(size_t)(row_base + tid) * NTILE + bx] =
        make_float4(v1, __int_as_float(i1), v2, __int_as_float(i2));
  }
}

// ---------------- K4: per-row candidate collect + fp64 exact rescore -> argmax ----------------
__global__ __launch_bounds__(256) void k_rescore(
    const float* __restrict__ A, const float* __restrict__ Wl,
    const float* __restrict__ bvec, const float* __restrict__ gum,
    const float4* __restrict__ top2g, int* __restrict__ ind) {
  const int row = blockIdx.x, tid = threadIdx.x;
  __shared__ int cidx[128];
  __shared__ int ccount;
  __shared__ float thr_s;
  __shared__ double red[256];
  if (tid == 0) ccount = 0;
  __syncthreads();
  float v1 = -INFINITY, v2 = -INFINITY;
  int i1 = 0, i2 = 0;
  if (tid < 64) {
    float4 e = top2g[(size_t)row * NTILE + tid];
    v1 = e.x; i1 = __float_as_int(e.y); v2 = e.z; i2 = __float_as_int(e.w);
    float g = v1;
#pragma unroll
    for (int d = 32; d; d >>= 1) g = fmaxf(g, __shfl_xor(g, d));
    if (tid == 0) thr_s = g - MARGIN;
  }
  __syncthreads();
  if (tid < 64) {
    float thr = thr_s;
    if (v1 >= thr) cidx[atomicAdd(&ccount, 1)] = i1;
    if (v2 >= thr) cidx[atomicAdd(&ccount, 1)] = i2;
  }
  __syncthreads();
  const int n = ccount;
  double bestv = -1e300; int besti = 0x7fffffff;
  const float* a = A + (size_t)row * K_DIM;
  for (int j = 0; j < n; ++j) {
    const int c = cidx[j];
    const float* w = Wl + (size_t)c * K_DIM;
    double s = 0.0;
    for (int k = tid; k < K_DIM; k += 256) s += (double)a[k] * (double)w[k];
    red[tid] = s; __syncthreads();
    for (int off = 128; off; off >>= 1) {
      if (tid < off) red[tid] += red[tid + off];
      __syncthreads();
    }
    if (tid == 0) {
      double z = red[0] + (double)bvec[c] + (double)gum[(size_t)row * C_DIM + c];
      if (z > bestv || (z == bestv && c < besti)) { bestv = z; besti = c; }
    }
    __syncthreads();
  }
  if (tid == 0) ind[row] = besti;
}

// ---------------- K5: gather codebook column ----------------
__global__ __launch_bounds__(256) void k_gather_T(const float* __restrict__ WcbT,
                                                  const int* __restrict__ ind,
                                                  float* __restrict__ out) {
  const int row = blockIdx.x;
  const int c = ind[row];
  const float4* src = reinterpret_cast<const float4*>(WcbT + (size_t)c * E_DIM);
  float4* dst = reinterpret_cast<float4*>(out + (size_t)row * E_DIM);
  dst[threadIdx.x] = src[threadIdx.x];  // 256 * 16B = 4KB row
}

__global__ __launch_bounds__(256) void k_gather_direct(const float* __restrict__ Wcb,
                                                       const int* __restrict__ ind,
                                                       float* __restrict__ out) {
  const int row = blockIdx.x;
  const int c = ind[row];
  for (int e = threadIdx.x; e < E_DIM; e += 256)
    out[(size_t)row * E_DIM + e] = Wcb[(size_t)e * C_DIM + c];
}

extern "C" void kernel_launch(void* const* d_in, const int* in_sizes, int n_in,
                              void* d_out, int out_size, void* d_ws, size_t ws_size,
                              hipStream_t stream) {
  const float* A   = (const float*)d_in[0];  // inputs (M x K)
  const float* Wl  = (const float*)d_in[1];  // W_logits (C x K)
  const float* bv  = (const float*)d_in[2];  // b_logits (C)
  const float* Wcb = (const float*)d_in[3];  // W_cb (E x C)
  const float* gum = (const float*)d_in[4];  // gumbel (M x C)
  float* out = (float*)d_out;

  char* ws = (char*)d_ws;
  size_t off = 0;
  unsigned short* Abf = (unsigned short*)(ws + off); off += (size_t)M_ROWS * K_DIM * 2;
  unsigned short* Wbf = (unsigned short*)(ws + off); off += (size_t)C_DIM * K_DIM * 2;
  float4* top2 = (float4*)(ws + off);                off += (size_t)M_ROWS * NTILE * 16;
  int* ind = (int*)(ws + off);                       off += (size_t)M_ROWS * 4;
  float* WcbT = (float*)(ws + off);
  const size_t need_full = off + (size_t)C_DIM * E_DIM * 4;
  const bool full = ws_size >= need_full;

  k_cvt_bf16<<<(M_ROWS * K_DIM / 4) / 256, 256, 0, stream>>>(A, Abf, M_ROWS * K_DIM / 4);
  k_cvt_bf16<<<(C_DIM * K_DIM / 4) / 256, 256, 0, stream>>>(Wl, Wbf, C_DIM * K_DIM / 4);
  if (full) {
    dim3 g(C_DIM / 32, E_DIM / 32);
    k_transpose<<<g, 256, 0, stream>>>(Wcb, WcbT);
  }
  k_gemm_top2<<<4096, 256, 0, stream>>>(Abf, Wbf, bv, gum, top2);
  k_rescore<<<M_ROWS, 256, 0, stream>>>(A, Wl, bv, gum, top2, ind);
  if (full) k_gather_T<<<M_ROWS, 256, 0, stream>>>(WcbT, ind, out);
  else      k_gather_direct<<<M_ROWS, 256, 0, stream>>>(Wcb, ind, out);
}